// Round 1
// 852.630 us; speedup vs baseline: 1.0174x; 1.0174x over previous
//
#include <hip/hip_runtime.h>
#include <float.h>

// Sparsemax rows of [4096, 32000] fp32.
//
// Single streaming pass shaped like a float4 copy kernel (measured 6.29 TB/s
// ceiling on MI355X): common path = load float4, store zero4, 3x v_max,
// 1x v_cmp, execz-skip. ALL bookkeeping (shared running-max refresh,
// candidate atomics) lives in a rare slow path gated on m4 > thr, where thr
// is a per-thread register refreshed only inside the slow path.
//
// Correctness of the filter: smax_key is a monotone shared lower bound on the
// row max, so any cached thr = est_local - 1 <= truemax - 1. For sparsemax,
// tau >= max - 1, so every support element satisfies v > truemax - 1 > thr at
// the moment it streams by => it takes the slow path and is recorded (with the
// freshly refreshed, still-conservative threshold). Stale thr only admits
// extra candidates, pruned later against the exact block max.

#define D     32000
#define D4    (D / 4)
#define BLOCK 256
#define CAP   2048   // raw candidates (expected ~60-80; >20x margin)
#define PCAP  512    // pruned candidates (> truemax-1; expected ~30)

__device__ __forceinline__ unsigned enc_f32(float f) {
    unsigned u = __float_as_uint(f);
    return (u & 0x80000000u) ? ~u : (u | 0x80000000u);
}
__device__ __forceinline__ float dec_f32(unsigned k) {
    unsigned u = (k & 0x80000000u) ? (k ^ 0x80000000u) : ~k;
    return __uint_as_float(u);
}

__global__ __launch_bounds__(BLOCK) void sparsemax_kernel(const float* __restrict__ X,
                                                          float* __restrict__ out) {
    const int row = blockIdx.x;
    const int tid = threadIdx.x;
    const size_t base = (size_t)row * D;
    const float4* __restrict__ x4 = (const float4*)(X + base);
    float4* __restrict__ o4 = (float4*)(out + base);

    __shared__ float    candV[CAP];
    __shared__ int      candI[CAP];
    __shared__ float    pv[PCAP];
    __shared__ int      pidx[PCAP];
    __shared__ float    ssorted[PCAP];
    __shared__ unsigned smax_key;
    __shared__ int      scount, scount2;
    __shared__ float    swarp[BLOCK / 64];
    __shared__ float    s_truemax, s_tau;

    if (tid == 0) { smax_key = 0u; scount = 0; scount2 = 0; }
    __syncthreads();

    const float4 zero4 = make_float4(0.f, 0.f, 0.f, 0.f);

    // ---- iteration 0: seed the shared max estimate ----
    float4 v0 = x4[tid];
    o4[tid] = zero4;
    float tmax = fmaxf(fmaxf(v0.x, v0.y), fmaxf(v0.z, v0.w));
    atomicMax(&smax_key, enc_f32(tmax));
    __syncthreads();   // est now covers the first 1024 elements (~3.2 for N(0,1))

    // Cached per-thread threshold; refreshed only in the slow path.
    float thr = dec_f32(*(volatile unsigned*)&smax_key) - 1.0f;

    // re-check iteration-0 values via the slow path
    if (tmax > thr) {
        int gi = tid * 4;
        if (v0.x > thr) { int p = atomicAdd(&scount, 1); if (p < CAP) { candV[p] = v0.x; candI[p] = gi + 0; } }
        if (v0.y > thr) { int p = atomicAdd(&scount, 1); if (p < CAP) { candV[p] = v0.y; candI[p] = gi + 1; } }
        if (v0.z > thr) { int p = atomicAdd(&scount, 1); if (p < CAP) { candV[p] = v0.z; candI[p] = gi + 2; } }
        if (v0.w > thr) { int p = atomicAdd(&scount, 1); if (p < CAP) { candV[p] = v0.w; candI[p] = gi + 3; } }
    }

    // ---- main streaming pass: copy-kernel-shaped common path ----
    for (int i = tid + BLOCK; i < D4; i += BLOCK) {
        float4 v = x4[i];
        o4[i] = zero4;
        float m4 = fmaxf(fmaxf(v.x, v.y), fmaxf(v.z, v.w));
        if (__builtin_expect(m4 > thr, 0)) {         // rare slow path
            if (m4 > tmax) { tmax = m4; atomicMax(&smax_key, enc_f32(tmax)); }
            thr = dec_f32(*(volatile unsigned*)&smax_key) - 1.0f;
            int gi = i * 4;
            if (v.x > thr) { int p = atomicAdd(&scount, 1); if (p < CAP) { candV[p] = v.x; candI[p] = gi + 0; } }
            if (v.y > thr) { int p = atomicAdd(&scount, 1); if (p < CAP) { candV[p] = v.y; candI[p] = gi + 1; } }
            if (v.z > thr) { int p = atomicAdd(&scount, 1); if (p < CAP) { candV[p] = v.z; candI[p] = gi + 2; } }
            if (v.w > thr) { int p = atomicAdd(&scount, 1); if (p < CAP) { candV[p] = v.w; candI[p] = gi + 3; } }
        }
    }
    __syncthreads();

    // ---- exact row max: block reduction of per-thread maxes ----
    float m = tmax;
    #pragma unroll
    for (int off = 32; off > 0; off >>= 1)
        m = fmaxf(m, __shfl_down(m, off, 64));
    if ((tid & 63) == 0) swarp[tid >> 6] = m;
    __syncthreads();
    if (tid == 0) {
        float mm = swarp[0];
        #pragma unroll
        for (int w = 1; w < BLOCK / 64; ++w) mm = fmaxf(mm, swarp[w]);
        s_truemax = mm;
    }
    __syncthreads();
    const float truemax = s_truemax;

    // ---- prune to exact candidate set (> max-1), store shifted ----
    int K = scount; if (K > CAP) K = CAP;
    const float fthr = truemax - 1.0f;
    for (int t = tid; t < K; t += BLOCK) {
        float v = candV[t];
        if (v > fthr) {
            int p = atomicAdd(&scount2, 1);
            if (p < PCAP) { pv[p] = v - truemax; pidx[p] = candI[t]; }
        }
    }
    __syncthreads();
    int K2 = scount2; if (K2 > PCAP) K2 = PCAP;

    // ---- rank sort (descending), K2 ~ 30 ----
    for (int t = tid; t < K2; t += BLOCK) {
        float v = pv[t];
        int rank = 0;
        for (int j = 0; j < K2; ++j) {
            float u = pv[j];
            rank += (u > v) || (u == v && j < t);
        }
        ssorted[rank] = v;
    }
    __syncthreads();

    // ---- tau (reference recurrence, shifted coords) ----
    if (tid == 0) {
        float cs = 0.0f, cs_k = 0.0f;
        int k = 1;
        for (int j = 0; j < K2; ++j) {
            cs += ssorted[j];
            if ((float)(j + 1) * ssorted[j] > cs - 1.0f) { k = j + 1; cs_k = cs; }
        }
        s_tau = (cs_k - 1.0f) / (float)k;
    }
    __syncthreads();
    const float tau = s_tau;

    // ---- scatter the ~k nonzero outputs ----
    for (int t = tid; t < K2; t += BLOCK) {
        float val = pv[t] - tau;
        if (val > 0.0f) out[base + pidx[t]] = val;
    }
}

extern "C" void kernel_launch(void* const* d_in, const int* in_sizes, int n_in,
                              void* d_out, int out_size, void* d_ws, size_t ws_size,
                              hipStream_t stream) {
    const float* X = (const float*)d_in[0];
    float* out = (float*)d_out;
    const int rows = in_sizes[0] / D;  // 4096
    sparsemax_kernel<<<rows, BLOCK, 0, stream>>>(X, out);
}

// Round 3
// 812.146 us; speedup vs baseline: 1.0681x; 1.0498x over previous
//
#include <hip/hip_runtime.h>
#include <float.h>

// Sparsemax rows of [4096, 32000] fp32.
//
// Single streaming pass shaped like a float4 copy kernel (measured 6.29 TB/s
// ceiling on MI355X): common path = nt-load 4xf32, nt-store 4x zero, 3x v_max,
// 1x v_cmp, execz-skip. Nontemporal accesses go through clang ext_vector
// (native vector) types -- __builtin_nontemporal_* rejects HIP_vector_type.
//
// Slow path (m4 > thr) has NO LDS-read stall: thr is refreshed only when a
// thread sets a personal record, using the OLD VALUE RETURNED by the LDS
// atomicMax (free global estimate). Between records thr goes stale, which is
// conservative: thr <= truemax-1 always, so every sparsemax support element
// (v > tau >= truemax-1 >= thr) takes the slow path and is recorded; stale
// thr only admits extra candidates, pruned later against the exact max.

#define D     32000
#define D4    (D / 4)
#define BLOCK 256
#define CAP   2048   // raw candidates (expected ~150-400; >5x margin)
#define PCAP  512    // pruned candidates (> truemax-1; expected ~30)

typedef float f32x4 __attribute__((ext_vector_type(4)));

__device__ __forceinline__ unsigned enc_f32(float f) {
    unsigned u = __float_as_uint(f);
    return (u & 0x80000000u) ? ~u : (u | 0x80000000u);
}
__device__ __forceinline__ float dec_f32(unsigned k) {
    unsigned u = (k & 0x80000000u) ? (k ^ 0x80000000u) : ~k;
    return __uint_as_float(u);
}

__global__ __launch_bounds__(BLOCK) void sparsemax_kernel(const float* __restrict__ X,
                                                          float* __restrict__ out) {
    const int row = blockIdx.x;
    const int tid = threadIdx.x;
    const size_t base = (size_t)row * D;
    const f32x4* __restrict__ x4 = (const f32x4*)(X + base);
    f32x4* __restrict__ o4 = (f32x4*)(out + base);

    __shared__ float    candV[CAP];
    __shared__ int      candI[CAP];
    __shared__ float    pv[PCAP];
    __shared__ int      pidx[PCAP];
    __shared__ float    ssorted[PCAP];
    __shared__ unsigned smax_key;
    __shared__ int      scount, scount2;
    __shared__ float    swarp[BLOCK / 64];
    __shared__ float    s_truemax, s_tau;

    if (tid == 0) { smax_key = 0u; scount = 0; scount2 = 0; }
    __syncthreads();

    const f32x4 zero4 = (f32x4)(0.0f);

    // ---- iteration 0: seed the shared max estimate ----
    f32x4 v0 = __builtin_nontemporal_load(&x4[tid]);
    __builtin_nontemporal_store(zero4, &o4[tid]);
    float tmax = fmaxf(fmaxf(v0.x, v0.y), fmaxf(v0.z, v0.w));
    atomicMax(&smax_key, enc_f32(tmax));
    __syncthreads();   // est now covers the first 1024 elements (~3.2 for N(0,1))

    // Per-thread cached threshold; refreshed only on personal-record events.
    float thr = dec_f32(smax_key) - 1.0f;

    // re-check iteration-0 values via the slow path
    if (tmax > thr) {
        int gi = tid * 4;
        if (v0.x > thr) { int p = atomicAdd(&scount, 1); if (p < CAP) { candV[p] = v0.x; candI[p] = gi + 0; } }
        if (v0.y > thr) { int p = atomicAdd(&scount, 1); if (p < CAP) { candV[p] = v0.y; candI[p] = gi + 1; } }
        if (v0.z > thr) { int p = atomicAdd(&scount, 1); if (p < CAP) { candV[p] = v0.z; candI[p] = gi + 2; } }
        if (v0.w > thr) { int p = atomicAdd(&scount, 1); if (p < CAP) { candV[p] = v0.w; candI[p] = gi + 3; } }
    }

    // ---- main streaming pass: copy-kernel-shaped common path ----
    #pragma unroll 2
    for (int i = tid + BLOCK; i < D4; i += BLOCK) {
        f32x4 v = __builtin_nontemporal_load(&x4[i]);
        __builtin_nontemporal_store(zero4, &o4[i]);
        float m4 = fmaxf(fmaxf(v.x, v.y), fmaxf(v.z, v.w));
        if (__builtin_expect(m4 > thr, 0)) {         // rare slow path
            if (m4 > tmax) {                          // personal record: refresh thr
                tmax = m4;                            // via the atomic's return value
                unsigned old = atomicMax(&smax_key, enc_f32(m4));
                thr = fmaxf(dec_f32(old), m4) - 1.0f;
            }
            int gi = i * 4;
            if (v.x > thr) { int p = atomicAdd(&scount, 1); if (p < CAP) { candV[p] = v.x; candI[p] = gi + 0; } }
            if (v.y > thr) { int p = atomicAdd(&scount, 1); if (p < CAP) { candV[p] = v.y; candI[p] = gi + 1; } }
            if (v.z > thr) { int p = atomicAdd(&scount, 1); if (p < CAP) { candV[p] = v.z; candI[p] = gi + 2; } }
            if (v.w > thr) { int p = atomicAdd(&scount, 1); if (p < CAP) { candV[p] = v.w; candI[p] = gi + 3; } }
        }
    }
    __syncthreads();

    // ---- exact row max: block reduction of per-thread maxes ----
    float m = tmax;
    #pragma unroll
    for (int off = 32; off > 0; off >>= 1)
        m = fmaxf(m, __shfl_down(m, off, 64));
    if ((tid & 63) == 0) swarp[tid >> 6] = m;
    __syncthreads();
    if (tid == 0) {
        float mm = swarp[0];
        #pragma unroll
        for (int w = 1; w < BLOCK / 64; ++w) mm = fmaxf(mm, swarp[w]);
        s_truemax = mm;
    }
    __syncthreads();
    const float truemax = s_truemax;

    // ---- prune to exact candidate set (> max-1), store shifted ----
    int K = scount; if (K > CAP) K = CAP;
    const float fthr = truemax - 1.0f;
    for (int t = tid; t < K; t += BLOCK) {
        float v = candV[t];
        if (v > fthr) {
            int p = atomicAdd(&scount2, 1);
            if (p < PCAP) { pv[p] = v - truemax; pidx[p] = candI[t]; }
        }
    }
    __syncthreads();
    int K2 = scount2; if (K2 > PCAP) K2 = PCAP;

    // ---- rank sort (descending), K2 ~ 30 ----
    for (int t = tid; t < K2; t += BLOCK) {
        float v = pv[t];
        int rank = 0;
        for (int j = 0; j < K2; ++j) {
            float u = pv[j];
            rank += (u > v) || (u == v && j < t);
        }
        ssorted[rank] = v;
    }
    __syncthreads();

    // ---- tau (reference recurrence, shifted coords) ----
    if (tid == 0) {
        float cs = 0.0f, cs_k = 0.0f;
        int k = 1;
        for (int j = 0; j < K2; ++j) {
            cs += ssorted[j];
            if ((float)(j + 1) * ssorted[j] > cs - 1.0f) { k = j + 1; cs_k = cs; }
        }
        s_tau = (cs_k - 1.0f) / (float)k;
    }
    __syncthreads();
    const float tau = s_tau;

    // ---- scatter the ~k nonzero outputs ----
    for (int t = tid; t < K2; t += BLOCK) {
        float val = pv[t] - tau;
        if (val > 0.0f) out[base + pidx[t]] = val;
    }
}

extern "C" void kernel_launch(void* const* d_in, const int* in_sizes, int n_in,
                              void* d_out, int out_size, void* d_ws, size_t ws_size,
                              hipStream_t stream) {
    const float* X = (const float*)d_in[0];
    float* out = (float*)d_out;
    const int rows = in_sizes[0] / D;  // 4096
    sparsemax_kernel<<<rows, BLOCK, 0, stream>>>(X, out);
}